// Round 12
// baseline (195.058 us; speedup 1.0000x reference)
//
#include <hip/hip_runtime.h>

#define B_  4
#define D_  512
#define H_  8
#define DV_ 64
#define S_  2048
#define LOG2E 1.442695041f

typedef __bf16 bf16;
typedef bf16  bf16x8 __attribute__((ext_vector_type(8)));
typedef bf16  bf16x4 __attribute__((ext_vector_type(4)));
typedef float f32x4  __attribute__((ext_vector_type(4)));

#define MFMA(a, b, c) __builtin_amdgcn_mfma_f32_16x16x32_bf16((a), (b), (c), 0, 0, 0)

// async global->LDS, 16B per lane; LDS dest is wave-uniform base + lane*16
#define GLOAD_LDS(g, l)                                                     \
    __builtin_amdgcn_global_load_lds(                                       \
        (const __attribute__((address_space(1))) void*)(g),                 \
        (__attribute__((address_space(3))) void*)(l), 16, 0, 0)

// s_waitcnt with vmcnt(n), lgkm/exp unconstrained (gfx9 encoding)
#define WAIT_VMCNT(n)                                                       \
    __builtin_amdgcn_s_waitcnt(((n) & 15) | (((n) >> 4) << 14) | (7 << 4) | (15 << 8))

// ---------------------------------------------------------------------------
// Kernel 1: prep (r8/r9-verified): 64x64 transpose tiles, float4 loads,
// bf16x8 stores + weight pack.
// ---------------------------------------------------------------------------
__global__ __launch_bounds__(256) void prep(
    const float* __restrict__ x, const float* __restrict__ Wq,
    const float* __restrict__ Wk, const float* __restrict__ Wv,
    const float* __restrict__ W0, bf16* __restrict__ xb, bf16* __restrict__ Wb) {
    const int bid = blockIdx.x;
    if (bid < 1024) {                            // transpose: B * D/64 * S/64
        __shared__ float tile[64][65];           // [s][d], 16640 B
        const int sblk = bid & 31;
        const int dblk = (bid >> 5) & 7;
        const int b    = bid >> 8;
        const int d0 = dblk * 64, s0 = sblk * 64;
        const int tx = threadIdx.x & 15;         // float4 col (s)
        const int ty = threadIdx.x >> 4;         // 0..15 (d row)
        const float* xp = x + (size_t)b * D_ * S_;
#pragma unroll
        for (int i = 0; i < 64; i += 16) {
            const float4 v = *(const float4*)&xp[(size_t)(d0 + ty + i) * S_ +
                                                 s0 + tx * 4];
            tile[tx * 4 + 0][ty + i] = v.x;
            tile[tx * 4 + 1][ty + i] = v.y;
            tile[tx * 4 + 2][ty + i] = v.z;
            tile[tx * 4 + 3][ty + i] = v.w;
        }
        __syncthreads();
        bf16* xbp = xb + ((size_t)b * S_ + s0) * D_ + d0;
        const int srow0 = threadIdx.x >> 3;      // 0..31
        const int d8    = (threadIdx.x & 7) * 8; // 0..56
#pragma unroll
        for (int i = 0; i < 2; ++i) {
            const int srow = srow0 + i * 32;
            bf16x8 hv;
#pragma unroll
            for (int j = 0; j < 8; ++j) hv[j] = (bf16)tile[srow][d8 + j];
            *(bf16x8*)&xbp[(size_t)srow * D_ + d8] = hv;
        }
    } else {                                     // weight-pack part: 256 blocks
        const int f0 = ((bid - 1024) * 256 + threadIdx.x) * 16;  // 0..1048560
        const int src = f0 >> 18;                // 262144 elems per matrix
        const int off = f0 & 262143;
        const float* W = (src == 0) ? Wq : (src == 1) ? Wk : (src == 2) ? Wv : W0;
        float4 v0 = *(const float4*)&W[off];
        float4 v1 = *(const float4*)&W[off + 4];
        float4 v2 = *(const float4*)&W[off + 8];
        float4 v3 = *(const float4*)&W[off + 12];
        bf16x8 h0 = {(bf16)v0.x, (bf16)v0.y, (bf16)v0.z, (bf16)v0.w,
                     (bf16)v1.x, (bf16)v1.y, (bf16)v1.z, (bf16)v1.w};
        bf16x8 h1 = {(bf16)v2.x, (bf16)v2.y, (bf16)v2.z, (bf16)v2.w,
                     (bf16)v3.x, (bf16)v3.y, (bf16)v3.z, (bf16)v3.w};
        *(bf16x8*)&Wb[f0]     = h0;
        *(bf16x8*)&Wb[f0 + 8] = h1;
    }
}

// ---------------------------------------------------------------------------
// Kernel 2: fused QKV GEMM — r10-verified (8 waves, dbuf T3-minimum K-loop,
// sigma-V, T1 XCD swizzle). Unchanged this round.
// ---------------------------------------------------------------------------
__global__ __launch_bounds__(512) void gemm_qkv(
    const bf16* __restrict__ A, const bf16* __restrict__ Wb,
    const float* __restrict__ bq, const float* __restrict__ bk,
    const float* __restrict__ bv,
    bf16* __restrict__ Q, bf16* __restrict__ K, bf16* __restrict__ Vt) {
    __shared__ union {
        struct { bf16 A[2][8192]; bf16 B[2][8192]; } s;  // 65536 B dbuf
        bf16 T[128][132];                        // epilogue transpose (33792 B)
    } sm;

    const int tid = threadIdx.x;
    const int w = tid >> 6, lane = tid & 63;
    const int m16 = lane & 15, quad = lane >> 4;
    const int wr = w & 1, wc = w >> 1;           // wc in 0..3 (32-col strip)

    const int bid  = (blockIdx.x & 7) * 96 + (blockIdx.x >> 3);  // T1 swizzle
    const int nblk = bid % 12;                   // N = 1536 / 128
    const int mblk = bid / 12;                   // M = 8192 / 128
    const int m0 = mblk * 128, n0 = nblk * 128;

#define QKV_STAGE(BUF, K0)                                                   \
    {                                                                        \
        const int cb_ = (w & 3) * 4;                                         \
        _Pragma("unroll")                                                    \
        for (int i_ = 0; i_ < 4; ++i_) {                                     \
            const int c_  = cb_ + i_;                                        \
            const int mt_ = c_ >> 1, kk_ = c_ & 1;                           \
            const int row_ = mt_ * 16 + m16;                                 \
            const int col_ = (K0) + kk_ * 32 + quad * 8;                     \
            if (w < 4)                                                       \
                GLOAD_LDS(&A[(size_t)(m0 + row_) * D_ + col_],               \
                          &sm.s.A[BUF][(c_ * 64 + lane) * 8]);               \
            else                                                             \
                GLOAD_LDS(&Wb[(size_t)(n0 + row_) * D_ + col_],              \
                          &sm.s.B[BUF][(c_ * 64 + lane) * 8]);               \
        }                                                                    \
    }

    f32x4 acc[4][2];
#pragma unroll
    for (int i = 0; i < 4; ++i)
#pragma unroll
        for (int j = 0; j < 2; ++j) acc[i][j] = (f32x4){0.f, 0.f, 0.f, 0.f};

    QKV_STAGE(0, 0);
    __syncthreads();                             // tile 0 visible

    for (int t = 0; t < 8; ++t) {
        const int cur = t & 1;
        if (t < 7) QKV_STAGE(cur ^ 1, (t + 1) * 64);
#pragma unroll
        for (int kk = 0; kk < 2; ++kk) {
            bf16x8 af[4], bfv[2];
#pragma unroll
            for (int tt = 0; tt < 4; ++tt)
                af[tt]  = *(const bf16x8*)&sm.s.A[cur][
                    (((wr * 4 + tt) * 2 + kk) * 64 + lane) * 8];
#pragma unroll
            for (int nt = 0; nt < 2; ++nt)
                bfv[nt] = *(const bf16x8*)&sm.s.B[cur][
                    (((wc * 2 + nt) * 2 + kk) * 64 + lane) * 8];
#pragma unroll
            for (int mt = 0; mt < 4; ++mt)
#pragma unroll
                for (int nt = 0; nt < 2; ++nt)
                    acc[mt][nt] = MFMA(af[mt], bfv[nt], acc[mt][nt]);
        }
        __syncthreads();                         // drains stage(t+1); buf flip
    }
#undef QKV_STAGE

    const int proj = n0 >> 9;                    // 128-tiles never straddle
    const float* bias = (proj == 0) ? bq : (proj == 1) ? bk : bv;

    if (proj == 2) {                             // V: direct sigma-swizzled store
#pragma unroll
        for (int mt = 0; mt < 4; ++mt)
#pragma unroll
            for (int nt = 0; nt < 2; ++nt) {
                const int nr = (n0 + wc * 32 + nt * 16 + m16) & 511;
                const int h = nr >> 6, e = nr & 63;
                const float bia = bias[nr];
                const int srow = m0 + wr * 64 + mt * 16 + quad * 4;
                const int b = srow >> 11, s = srow & 2047;
                const int s2 = (s & ~31) | (quad * 8 + (mt & 1) * 4);  // sigma
                bf16x4 hv;
#pragma unroll
                for (int r = 0; r < 4; ++r) hv[r] = (bf16)(acc[mt][nt][r] + bia);
                *(bf16x4*)&Vt[(((size_t)b * H_ + h) * DV_ + e) * S_ + s2] = hv;
            }
    } else {                                     // Q/K: LDS transpose -> bf16x8
#pragma unroll
        for (int mt = 0; mt < 4; ++mt)
#pragma unroll
            for (int nt = 0; nt < 2; ++nt) {
                const int nloc = wc * 32 + nt * 16 + m16;
                const float bia = bias[(n0 + nloc) & 511];
#pragma unroll
                for (int r = 0; r < 4; ++r)
                    sm.T[wr * 64 + mt * 16 + quad * 4 + r][nloc] =
                        (bf16)(acc[mt][nt][r] + bia);
            }
        __syncthreads();
        const int rloc = tid >> 2, cb = (tid & 3) * 32;
        const int M = m0 + rloc, b = M >> 11, s = M & 2047;
        const int nrb = (n0 + cb) & 511;
        const int h = nrb >> 6, eo = nrb & 63;   // 32-chunk offset within head
        bf16* dst = ((proj == 0) ? Q : K) +
                    (((size_t)b * H_ + h) * S_ + s) * DV_ + eo;
#pragma unroll
        for (int u = 0; u < 4; ++u)
            *(bf16x8*)&dst[u * 8] = *(const bf16x8*)&sm.T[rloc][cb + u * 8];
    }
}

// ---------------------------------------------------------------------------
// Kernel 3: flash attention — r4/r10 structure VERBATIM (verified 64.2us).
// r12 DIAGNOSTIC: grid split into two 512-block dispatches via `base` param
// (blocks fully independent; 512 blocks = same 2 blocks/CU occupancy each).
// Purpose: (a) flash halves ~32-34us each -> any other kernel >34us now
// surfaces in rocprof top-5 with counters; (b) delta-total vs r10's 191.0
// directly measures ONE extra dispatch's overhead, deciding the
// launch-overhead vs small-K-GEMM theory quantitatively.
// ---------------------------------------------------------------------------
__global__ __launch_bounds__(256, 2) void flash_attn(
    const bf16* __restrict__ Q, const bf16* __restrict__ K, const bf16* __restrict__ Vt,
    const float* __restrict__ mask, bf16* __restrict__ heads, int base) {
    __shared__ union {
        struct {
            bf16 Kl[2][4][2048];                 // [buf][wave][32 keys x 64 d]
            bf16 Vl[2][4][2048];                 // [buf][wave][64 e x 32 keys]
            float Ms[2048];                      // mask * log2(e)
        } s;
        struct { float O[64][65]; float L[64]; } red;
    } sm;

    // XCD-aware swizzle: contiguous 128-block chunk per XCD (K/V L2 locality)
    const int bid  = blockIdx.x + base;          // 0..1023 across 2 dispatches
    const int bidx = (bid & 7) * 128 + (bid >> 3);
    const int qblk = bidx & 31;
    const int h    = (bidx >> 5) & 7;
    const int b    = bidx >> 8;
    const int q0   = qblk * 64;

    const int tid = threadIdx.x;
    const int w = tid >> 6, lane = tid & 63;
    const int m16 = lane & 15, quad = lane >> 4;

    const bf16* Qp = Q  + ((size_t)b * H_ + h) * S_ * DV_;
    const bf16* Kp = K  + ((size_t)b * H_ + h) * S_ * DV_;
    const bf16* Vp = Vt + ((size_t)b * H_ + h) * DV_ * S_;
    const float* mp = mask + (size_t)b * S_;

    // per-lane staging constants (swizzle algebra, r1-verified)
    const int krow = lane >> 3;                          // 0..7
    const int kcol = ((lane & 7) ^ krow) * 8;            // elem offset in K row
    const int vrow = lane >> 2;                          // 0..15
    const int vcol = ((lane & 3) ^ (vrow & 3)) * 8;      // elem offset in V row

    // stage mask to LDS pre-scaled into the exp2 domain (retires pre-barrier)
#pragma unroll
    for (int p = 0; p < 2; ++p) {
        const float4 mv = *(const float4*)&mp[(p * 256 + tid) * 4];
        f32x4 t = {mv.x * LOG2E, mv.y * LOG2E, mv.z * LOG2E, mv.w * LOG2E};
        *(f32x4*)&sm.s.Ms[(p * 256 + tid) * 4] = t;
    }

    // Q B-frags for 64 q-rows, pre-scaled by 1/sqrt(64) (exact in bf16)
    bf16x8 qf[4][2];
#pragma unroll
    for (int qt = 0; qt < 4; ++qt)
#pragma unroll
        for (int kk = 0; kk < 2; ++kk) {
            bf16x8 v = *(const bf16x8*)&Qp[(size_t)(q0 + qt * 16 + m16) * DV_ +
                                           kk * 32 + quad * 8];
#pragma unroll
            for (int i = 0; i < 8; ++i) v[i] = (bf16)((float)v[i] * 0.125f);
            qf[qt][kk] = v;
        }

    bf16x8 ones;
#pragma unroll
    for (int i = 0; i < 8; ++i) ones[i] = (bf16)1.0f;

    f32x4 o[4][4];                               // O^T[e=16mt+4quad+r][q=16qt+m16]
    f32x4 lacc[4];
#pragma unroll
    for (int mt = 0; mt < 4; ++mt)
#pragma unroll
        for (int qt = 0; qt < 4; ++qt) o[mt][qt] = (f32x4){0.f, 0.f, 0.f, 0.f};
#pragma unroll
    for (int qt = 0; qt < 4; ++qt) lacc[qt] = (f32x4){0.f, 0.f, 0.f, 0.f};

    // ---- prologue: batch 0 (buf 0), K first then V; barrier drains vmcnt ----
    {
        const int tw = w * 32;
#pragma unroll
        for (int p = 0; p < 4; ++p)
            GLOAD_LDS(&Kp[(size_t)(tw + p * 8 + krow) * DV_ + kcol],
                      &sm.s.Kl[0][w][(p * 64 + lane) * 8]);
#pragma unroll
        for (int p = 0; p < 4; ++p)
            GLOAD_LDS(&Vp[(size_t)(p * 16 + vrow) * S_ + tw + vcol],
                      &sm.s.Vl[0][w][(p * 64 + lane) * 8]);
    }
    __syncthreads();                             // mask visible; batch0 done

    for (int i = 0; i < 16; ++i) {
        const int tw = i * 128 + w * 32;         // this wave's 32 keys
        if (i < 15) {                            // issue batch i+1 -> buf (i+1)&1
            const int twn = tw + 128;
            const int nb = (i + 1) & 1;
#pragma unroll
            for (int p = 0; p < 4; ++p)
                GLOAD_LDS(&Kp[(size_t)(twn + p * 8 + krow) * DV_ + kcol],
                          &sm.s.Kl[nb][w][(p * 64 + lane) * 8]);
#pragma unroll
            for (int p = 0; p < 4; ++p)
                GLOAD_LDS(&Vp[(size_t)(p * 16 + vrow) * S_ + twn + vcol],
                          &sm.s.Vl[nb][w][(p * 64 + lane) * 8]);
            WAIT_VMCNT(12);                      // K(i) in LDS (V(i) may lag)
        } else {
            WAIT_VMCNT(4);                       // K(15) in LDS
        }
        __builtin_amdgcn_sched_barrier(0);
        const int buf = i & 1;

        // K A-frags from LDS (swizzle-inverted: retrieves chunk kk*4+quad)
        bf16x8 kf[2][2];
#pragma unroll
        for (int tt = 0; tt < 2; ++tt)
#pragma unroll
            for (int kk = 0; kk < 2; ++kk)
                kf[tt][kk] = *(const bf16x8*)&sm.s.Kl[buf][w][
                    ((tt * 16 + m16) * 8 + ((kk * 4 + quad) ^ (m16 & 7))) * 8];
        const f32x4 m2a = *(const f32x4*)&sm.s.Ms[tw + quad * 4];
        const f32x4 m2b = *(const f32x4*)&sm.s.Ms[tw + 16 + quad * 4];

        // S^T tiles: sc[tt][qt], lane = p[t=16tt+4quad+r][q=16qt+m16]
        f32x4 sc[2][4];
#pragma unroll
        for (int tt = 0; tt < 2; ++tt)
#pragma unroll
            for (int qt = 0; qt < 4; ++qt) sc[tt][qt] = (f32x4){0.f, 0.f, 0.f, 0.f};
#pragma unroll
        for (int kk = 0; kk < 2; ++kk)
#pragma unroll
            for (int tt = 0; tt < 2; ++tt)
#pragma unroll
                for (int qt = 0; qt < 4; ++qt)
                    sc[tt][qt] = MFMA(kf[tt][kk], qf[qt][kk], sc[tt][qt]);

        // mask + exp2, directly into PV B-frags (in-lane, no LDS)
        f32x4 ngA, ngB;
#pragma unroll
        for (int r = 0; r < 4; ++r) {
            ngA[r] = (m2a[r] - LOG2E) * 8e29f;   // 0 for m=1, -1.15e30 for m=0
            ngB[r] = (m2b[r] - LOG2E) * 8e29f;
        }
        bf16x8 pf[4];
#pragma unroll
        for (int qt = 0; qt < 4; ++qt)
#pragma unroll
            for (int r = 0; r < 4; ++r) {
                pf[qt][r]     = (bf16)__builtin_amdgcn_exp2f(
                    __builtin_fmaf(sc[0][qt][r], m2a[r], ngA[r]));
                pf[qt][4 + r] = (bf16)__builtin_amdgcn_exp2f(
                    __builtin_fmaf(sc[1][qt][r], m2b[r], ngB[r]));
            }

        // l accumulation needs no V — overlap with V landing
#pragma unroll
        for (int qt = 0; qt < 4; ++qt) lacc[qt] = MFMA(ones, pf[qt], lacc[qt]);

        if (i < 15) WAIT_VMCNT(8);               // V(i) in LDS
        else        WAIT_VMCNT(0);
        __builtin_amdgcn_sched_barrier(0);

        // V A-frags from LDS (retrieves chunk quad)
        bf16x8 vf[4];
#pragma unroll
        for (int mt = 0; mt < 4; ++mt)
            vf[mt] = *(const bf16x8*)&sm.s.Vl[buf][w][
                ((mt * 16 + m16) * 4 + (quad ^ (m16 & 3))) * 8];

        // PV
#pragma unroll
        for (int mt = 0; mt < 4; ++mt)
#pragma unroll
            for (int qt = 0; qt < 4; ++qt) o[mt][qt] = MFMA(vf[mt], pf[qt], o[mt][qt]);
    }

    // ---- cross-wave reduction (turn-based accumulate into red) ----
    __syncthreads();
#pragma unroll
    for (int ww = 0; ww < 4; ++ww) {
        if (w == ww) {
#pragma unroll
            for (int mt = 0; mt < 4; ++mt)
#pragma unroll
                for (int qt = 0; qt < 4; ++qt)
#pragma unroll
                    for (int r = 0; r < 4; ++r) {
                        float* slot = &sm.red.O[mt * 16 + quad * 4 + r][qt * 16 + m16];
                        *slot = (ww == 0) ? o[mt][qt][r] : (*slot + o[mt][qt][r]);
                    }
            if (quad == 0)
#pragma unroll
                for (int qt = 0; qt < 4; ++qt) {
                    float* ls = &sm.red.L[qt * 16 + m16];
                    *ls = (ww == 0) ? lacc[qt][0] : (*ls + lacc[qt][0]);
                }
        }
        __syncthreads();
    }

    // ---- final store: thread -> (q = tid>>2, 16-wide e-chunk = (tid&3)*16) ----
    const int ql = tid >> 2, ec = (tid & 3) * 16;
    const float l  = sm.red.L[ql];
    const float qm = mp[q0 + ql];
    const float inv = qm / l;
    bf16x8 hv[2];
#pragma unroll
    for (int c = 0; c < 2; ++c)
#pragma unroll
        for (int i = 0; i < 8; ++i)
            hv[c][i] = (bf16)(sm.red.O[ec + c * 8 + i][ql] * inv);
    bf16* dst = &heads[((size_t)b * S_ + q0 + ql) * D_ + h * DV_ + ec];
    *(bf16x8*)(dst)     = hv[0];
    *(bf16x8*)(dst + 8) = hv[1];
}

// ---------------------------------------------------------------------------
// Kernel 4: out projection — r10-verified (8 waves, dbuf). Unchanged.
// ---------------------------------------------------------------------------
__global__ __launch_bounds__(512) void gemm_out(
    const bf16* __restrict__ A, const bf16* __restrict__ Wb,
    const float* __restrict__ b0, float* __restrict__ outp) {
    __shared__ bf16 Asl[2][8192];
    __shared__ bf16 Bsl[2][8192];

    const int tid = threadIdx.x;
    const int w = tid >> 6, lane = tid & 63;
    const int m16 = lane & 15, quad = lane >> 4;
    const int wr = w & 1, wc = w >> 1;           // wc in 0..3 (32-col strip)

    const int bid  = (blockIdx.x & 7) * 32 + (blockIdx.x >> 3);  // T1 swizzle
    const int nblk = bid & 3;                    // N = 512 / 128
    const int mblk = bid >> 2;                   // M = 8192 / 128
    const int m0 = mblk * 128, n0 = nblk * 128;

#define OUT_STAGE(BUF, K0)                                                   \
    {                                                                        \
        const int cb_ = (w & 3) * 4;                                         \
        _Pragma("unroll")                                                    \
        for (int i_ = 0; i_ < 4; ++i_) {                                     \
            const int c_  = cb_ + i_;                                        \
            const int mt_ = c_ >> 1, kk_ = c_ & 1;                           \
            const int row_ = mt_ * 16 + m16;                                 \
            const int col_ = (K0) + kk_ * 32 + quad * 8;                     \
            if (w < 4)                                                       \
                GLOAD_LDS(&A[(size_t)(m0 + row_) * D_ + col_],               \
                          &Asl[BUF][(c_ * 64 + lane) * 8]);                  \
            else                                                             \
                GLOAD_LDS(&Wb[(size_t)(1536 + n0 + row_) * D_ + col_],       \
                          &Bsl[BUF][(c_ * 64 + lane) * 8]);                  \
        }                                                                    \
    }

    f32x4 acc[4][2];
#pragma unroll
    for (int i = 0; i < 4; ++i)
#pragma unroll
        for (int j = 0; j < 2; ++j) acc[i][j] = (f32x4){0.f, 0.f, 0.f, 0.f};

    OUT_STAGE(0, 0);
    __syncthreads();

    for (int t = 0; t < 8; ++t) {
        const int cur = t & 1;
        if (t < 7) OUT_STAGE(cur ^ 1, (t + 1) * 64);
#pragma unroll
        for (int kk = 0; kk < 2; ++kk) {
            bf16x8 af[4], bfv[2];
#pragma unroll
            for (int tt = 0; tt < 4; ++tt)
                af[tt]  = *(const bf16x8*)&Asl[cur][
                    (((wr * 4 + tt) * 2 + kk) * 64 + lane) * 8];
#pragma unroll
            for (int nt = 0; nt < 2; ++nt)
                bfv[nt] = *(const bf16x8*)&Bsl[cur][
                    (((wc * 2 + nt) * 2 + kk) * 64 + lane) * 8];
#pragma unroll
            for (int mt = 0; mt < 4; ++mt)
#pragma unroll
                for (int nt = 0; nt < 2; ++nt)
                    acc[mt][nt] = MFMA(af[mt], bfv[nt], acc[mt][nt]);
        }
        __syncthreads();
    }
#undef OUT_STAGE

#pragma unroll
    for (int mt = 0; mt < 4; ++mt)
#pragma unroll
        for (int nt = 0; nt < 2; ++nt) {
            const int n = n0 + wc * 32 + nt * 16 + m16;
            const float bia = b0[n];
            const int srow = m0 + wr * 64 + mt * 16 + quad * 4;
            const int b = srow >> 11, s = srow & 2047;
            float4 vv;
            vv.x = acc[mt][nt][0] + bia;
            vv.y = acc[mt][nt][1] + bia;
            vv.z = acc[mt][nt][2] + bia;
            vv.w = acc[mt][nt][3] + bia;
            *(float4*)&outp[((size_t)b * D_ + n) * S_ + s] = vv;
        }
}

// ---------------------------------------------------------------------------
extern "C" void kernel_launch(void* const* d_in, const int* in_sizes, int n_in,
                              void* d_out, int out_size, void* d_ws, size_t ws_size,
                              hipStream_t stream) {
    const float* x    = (const float*)d_in[0];
    const float* mask = (const float*)d_in[1];
    const float* Wq   = (const float*)d_in[2];
    const float* bq   = (const float*)d_in[3];
    const float* Wk   = (const float*)d_in[4];
    const float* bk   = (const float*)d_in[5];
    const float* Wv   = (const float*)d_in[6];
    const float* bv   = (const float*)d_in[7];
    const float* W0   = (const float*)d_in[8];
    const float* b0   = (const float*)d_in[9];
    float* out = (float*)d_out;

    char* ws = (char*)d_ws;
    const size_t SEG = (size_t)B_ * S_ * D_ * sizeof(bf16);   // 8 MiB
    bf16* xb    = (bf16*)(ws);            // reused as `heads` after gemm_qkv
    bf16* Qb    = (bf16*)(ws + SEG);
    bf16* Kb    = (bf16*)(ws + 2 * SEG);
    bf16* Vt    = (bf16*)(ws + 3 * SEG);
    bf16* Wb    = (bf16*)(ws + 4 * SEG);  // 2048x512 bf16 = 2 MiB
    bf16* heads = xb;

    prep<<<dim3(1024 + 256), dim3(256), 0, stream>>>(x, Wq, Wk, Wv, W0, xb, Wb);
    gemm_qkv<<<dim3(64 * 12), dim3(512), 0, stream>>>(xb, Wb, bq, bk, bv, Qb, Kb, Vt);
    flash_attn<<<dim3(512), dim3(256), 0, stream>>>(Qb, Kb, Vt, mask, heads, 0);
    flash_attn<<<dim3(512), dim3(256), 0, stream>>>(Qb, Kb, Vt, mask, heads, 512);
    gemm_out<<<dim3(64 * 4), dim3(512), 0, stream>>>(heads, Wb, b0, out);
}